// Round 4
// baseline (631.540 us; speedup 1.0000x reference)
//
#include <hip/hip_runtime.h>
#include <hip/hip_bf16.h>
#include <cstdint>

// Problem constants (fixed by the reference harness)
#define NN 32768      // nodes per graph
#define EE 262144     // edges per graph
#define MM 65536      // 2*NN combined rows
#define HH 512
#define BB 64
#define DIN 20
#define BN_EPS 1e-5f

// ---------- bf16 helpers (bit-level, fast) ----------
__device__ __forceinline__ float bflo(uint32_t w) { return __builtin_bit_cast(float, w << 16); }
__device__ __forceinline__ float bfhi(uint32_t w) { return __builtin_bit_cast(float, w & 0xffff0000u); }
__device__ __forceinline__ uint32_t f2bf_u(float f) {
  uint32_t u = __builtin_bit_cast(uint32_t, f);
  return (u + 0x7fffu + ((u >> 16) & 1u)) >> 16;   // RTNE
}
__device__ __forceinline__ uint32_t pack2(float lo, float hi) {
  return f2bf_u(lo) | (f2bf_u(hi) << 16);
}

typedef __bf16 bf16x8 __attribute__((ext_vector_type(8)));
typedef float f32x4 __attribute__((ext_vector_type(4)));

__device__ __forceinline__ void gl2lds16(const void* g, void* l) {
  __builtin_amdgcn_global_load_lds(
      (const __attribute__((address_space(1))) void*)g,
      (__attribute__((address_space(3))) void*)l, 16, 0, 0);
}

// ---------- prep: W1/W2 fp32 [k][n] -> bf16 transposed [n][k] ----------
__global__ void prep_w(const float* __restrict__ W1, const float* __restrict__ W2,
                       uint16_t* __restrict__ Wt1, uint16_t* __restrict__ Wt2) {
  int idx = blockIdx.x * 256 + threadIdx.x;     // < 2*512*512
  int which = idx >> 18;
  int i = idx & 0x3ffff;
  int n = i >> 9, k = i & 511;
  const float* W = which ? W2 : W1;
  uint16_t* Wt = which ? Wt2 : Wt1;
  Wt[i] = (uint16_t)f2bf_u(W[(size_t)k * HH + n]);
}

// ---------- CSR build ----------
__global__ void deg_kernel(const int* __restrict__ dst1, const int* __restrict__ dst2,
                           int* __restrict__ deg_cnt) {
  int e = blockIdx.x * 256 + threadIdx.x;       // < 2*EE
  int g = e >> 18, le = e & 0x3ffff;
  int d = (g ? dst2 : dst1)[le];
  atomicAdd(&deg_cnt[g * NN + d], 1);
}

__global__ void scan_kernel(const int* __restrict__ deg_cnt, int* __restrict__ offsets,
                            int* __restrict__ cursor) {
  int g = blockIdx.x;
  const int* d = deg_cnt + g * NN;
  int* off = offsets + g * (NN + 1);
  int* cur = cursor + g * NN;
  int t = threadIdx.x;                          // 1024 threads
  int base = t * 32;
  int loc[32]; int s = 0;
#pragma unroll
  for (int i = 0; i < 32; i++) { loc[i] = d[base + i]; s += loc[i]; }
  __shared__ int sm[1024];
  sm[t] = s; __syncthreads();
  for (int ofs = 1; ofs < 1024; ofs <<= 1) {
    int v = sm[t];
    int add = (t >= ofs) ? sm[t - ofs] : 0;
    __syncthreads();
    sm[t] = v + add;
    __syncthreads();
  }
  int run = (t == 0) ? 0 : sm[t - 1];
#pragma unroll
  for (int i = 0; i < 32; i++) { off[base + i] = run; cur[base + i] = run; run += loc[i]; }
  if (t == 1023) off[NN] = run;
}

__global__ void scatter_kernel(const int* __restrict__ src1, const int* __restrict__ dst1,
                               const int* __restrict__ src2, const int* __restrict__ dst2,
                               int* __restrict__ cursor, int* __restrict__ csr) {
  int e = blockIdx.x * 256 + threadIdx.x;       // < 2*EE
  int g = e >> 18, le = e & 0x3ffff;
  int d = (g ? dst2 : dst1)[le];
  int s = (g ? src2 : src1)[le];
  int pos = atomicAdd(&cursor[g * NN + d], 1);
  csr[g * EE + pos] = s;
}

// ---------- xagg: xa = x + mean_{in-neighbors} x  (fp32, 20-dim; x fits in L2) ----------
__global__ void xagg_kernel(const float* __restrict__ x1, const float* __restrict__ x2,
                            const int* __restrict__ csr, const int* __restrict__ offsets,
                            float* __restrict__ xa) {
  int nid = blockIdx.x * 256 + threadIdx.x;     // [0, MM)
  int g = nid >> 15, n = nid & (NN - 1);
  const float* xg = g ? x2 : x1;
  const int* off = offsets + g * (NN + 1);
  int e0 = off[n], e1 = off[n + 1];
  const int* cs = csr + g * EE;
  float4 a4[5] = {};
  for (int e = e0; e < e1; e++) {
    const float4* xr = (const float4*)(xg + (size_t)cs[e] * DIN);
#pragma unroll
    for (int k = 0; k < 5; k++) {
      float4 v = xr[k];
      a4[k].x += v.x; a4[k].y += v.y; a4[k].z += v.z; a4[k].w += v.w;
    }
  }
  float inv = (e1 > e0) ? 1.f / (float)(e1 - e0) : 0.f;
  const float4* xs = (const float4*)(xg + (size_t)n * DIN);
  float4* xo = (float4*)(xa + (size_t)nid * DIN);
#pragma unroll
  for (int k = 0; k < 5; k++) {
    float4 v = xs[k];
    float4 o;
    o.x = v.x + a4[k].x * inv; o.y = v.y + a4[k].y * inv;
    o.z = v.z + a4[k].z * inv; o.w = v.w + a4[k].w * inv;
    xo[k] = o;
  }
}

// ---------- h0u: u1 = xa @ Wi + bi*(1+[deg>0])  (fp32 in, bf16 out) ----------
__global__ __launch_bounds__(256) void h0u_kernel(const float* __restrict__ xa,
                          const float* __restrict__ Wi, const float* __restrict__ bi,
                          const int* __restrict__ offsets, uint16_t* __restrict__ u) {
  int t = threadIdx.x;
  int col0 = (t & 127) * 4;         // 128 threads cover 512 cols
  int rhalf = t >> 7;               // two row-interleaved halves
  int r0 = blockIdx.x * 128;        // 512 blocks x 128 rows; never straddles graphs
  int g = r0 >> 15;
  const int* off = offsets + g * (NN + 1);

  float w[DIN][4];
#pragma unroll
  for (int k = 0; k < DIN; k++) {
    float4 wv = *(const float4*)(Wi + (size_t)k * HH + col0);
    w[k][0] = wv.x; w[k][1] = wv.y; w[k][2] = wv.z; w[k][3] = wv.w;
  }
  float4 bv = *(const float4*)(bi + col0);

  for (int rr = 0; rr < 64; rr++) {
    int row = rr * 2 + rhalf;       // uniform within a wave
    int grow = r0 + row;
    int n = grow & (NN - 1);
    float bf = (off[n + 1] - off[n] > 0) ? 2.f : 1.f;   // wave-uniform
    const float* xr = xa + (size_t)grow * DIN;
    float a0 = bv.x * bf, a1 = bv.y * bf, a2 = bv.z * bf, a3 = bv.w * bf;
#pragma unroll
    for (int k = 0; k < DIN; k++) {
      float xv = xr[k];             // wave-uniform -> s_load broadcast
      a0 = fmaf(xv, w[k][0], a0);
      a1 = fmaf(xv, w[k][1], a1);
      a2 = fmaf(xv, w[k][2], a2);
      a3 = fmaf(xv, w[k][3], a3);
    }
    uint2 o;
    o.x = pack2(a0, a1); o.y = pack2(a2, a3);
    *(uint2*)(u + (size_t)grow * HH + col0) = o;
  }
}

// ---------- aggbn: u2 = bnrelu(z1) + mean_{nbr} bnrelu(z1_j)  (one wave per node) ----------
__global__ void aggbn_kernel(const uint16_t* __restrict__ z, uint16_t* __restrict__ u,
                             const int* __restrict__ csr, const int* __restrict__ offsets,
                             const float* __restrict__ scsh) {
  int wid = (blockIdx.x * 256 + threadIdx.x) >> 6;   // node id in [0, MM)
  int lane = threadIdx.x & 63;
  int g = wid >> 15, n = wid & (NN - 1);
  const int* off = offsets + g * (NN + 1);
  int e0 = off[n], e1 = off[n + 1];
  const int* cs = csr + g * EE;
  const uint32_t* hb = (const uint32_t*)z;           // 256 u32 per row
  const float4* ssp = (const float4*)(scsh + (size_t)g * HH * 2 + lane * 16);
  float4 ss0 = ssp[0], ss1 = ssp[1], ss2 = ssp[2], ss3 = ssp[3];
  float sc[8] = {ss0.x, ss0.z, ss1.x, ss1.z, ss2.x, ss2.z, ss3.x, ss3.z};
  float sh[8] = {ss0.y, ss0.w, ss1.y, ss1.w, ss2.y, ss2.w, ss3.y, ss3.w};
  float acc[8] = {0.f, 0.f, 0.f, 0.f, 0.f, 0.f, 0.f, 0.f};
  for (int e = e0; e < e1; e++) {
    int s = cs[e];
    uint4 v = *(const uint4*)(hb + ((size_t)(g * NN + s)) * 256 + lane * 4);
    uint32_t wv[4] = {v.x, v.y, v.z, v.w};
#pragma unroll
    for (int i = 0; i < 4; i++) {
      acc[2 * i]     += fmaxf(fmaf(bflo(wv[i]), sc[2 * i],     sh[2 * i]),     0.f);
      acc[2 * i + 1] += fmaxf(fmaf(bfhi(wv[i]), sc[2 * i + 1], sh[2 * i + 1]), 0.f);
    }
  }
  float inv = (e1 > e0) ? 1.f / (float)(e1 - e0) : 0.f;
  uint4 hv = *(const uint4*)(hb + (size_t)wid * 256 + lane * 4);
  uint32_t wv[4] = {hv.x, hv.y, hv.z, hv.w};
  float o[8];
#pragma unroll
  for (int i = 0; i < 4; i++) {
    o[2 * i]     = fmaxf(fmaf(bflo(wv[i]), sc[2 * i],     sh[2 * i]),     0.f) + acc[2 * i] * inv;
    o[2 * i + 1] = fmaxf(fmaf(bfhi(wv[i]), sc[2 * i + 1], sh[2 * i + 1]), 0.f) + acc[2 * i + 1] * inv;
  }
  uint4 ov;
  ov.x = pack2(o[0], o[1]); ov.y = pack2(o[2], o[3]); ov.z = pack2(o[4], o[5]); ov.w = pack2(o[6], o[7]);
  *(uint4*)((uint32_t*)u + (size_t)wid * 256 + lane * 4) = ov;
}

// ---------- GEMM: C[M,512] = A[M,512](bf16) @ Wt^T + bias, fused BN stats ----------
// 128x128 tile, BK=64 (8 k-iters, half the barrier drains of BK=32), 4 waves (2x2),
// XOR-swizzled LDS: element (r,k) at r*64 + (( (k>>3) ^ (r&7) )*8 + (k&7)).
// Swizzle carried on the gl2lds GLOBAL addresses (LDS side stays base+lane*16);
// fragment ds_read_b128 then spreads each quad's 16 lanes over all 8 bank groups
// (2 lanes/bank = free) instead of the 8-16-way conflict of the naive layout.
__global__ __launch_bounds__(256) void gemm_kernel(const uint16_t* __restrict__ A,
                                                   const uint16_t* __restrict__ Bt,
                                                   const float* __restrict__ bias,
                                                   uint16_t* __restrict__ C,
                                                   float* __restrict__ stats) {
  __shared__ uint16_t sA[128 * 64];
  __shared__ uint16_t sB[128 * 64];
  const int tid = threadIdx.x;
  const int wave = tid >> 6;
  const int lane = tid & 63;
  const int m0 = blockIdx.x * 128;
  const int n0 = blockIdx.y * 128;
  const int fm = lane & 15;
  const int fm7 = fm & 7;
  const int quad = lane >> 4;
  const int wr = wave >> 1, wc = wave & 1;

  // staging: lane covers (r_loc = lane>>3, k8 slot = lane&7); global k8 is XORed
  const int r_loc = lane >> 3;
  const int k8slot = lane & 7;
  const int k8g = k8slot ^ r_loc;               // (r&7)==r_loc for 8-row-aligned chunks
  const int rbase = wave * 32;                  // wave stages rows [wave*32, wave*32+32)

  f32x4 acc[4][4] = {};
  for (int k0 = 0; k0 < HH; k0 += 64) {
    __syncthreads();
#pragma unroll
    for (int t = 0; t < 4; t++) {
      int R = rbase + t * 8 + r_loc;
      gl2lds16(A  + (size_t)(m0 + R) * HH + k0 + k8g * 8, &sA[R * 64 + k8slot * 8]);
      gl2lds16(Bt + (size_t)(n0 + R) * HH + k0 + k8g * 8, &sB[R * 64 + k8slot * 8]);
    }
    __syncthreads();
#pragma unroll
    for (int s2 = 0; s2 < 2; s2++) {
      const int k8 = s2 * 4 + quad;
      bf16x8 a[4], b[4];
#pragma unroll
      for (int i = 0; i < 4; i++) {
        int r = wr * 64 + i * 16 + fm;
        a[i] = *(const bf16x8*)&sA[r * 64 + ((k8 ^ fm7) * 8)];
      }
#pragma unroll
      for (int j = 0; j < 4; j++) {
        int r = wc * 64 + j * 16 + fm;
        b[j] = *(const bf16x8*)&sB[r * 64 + ((k8 ^ fm7) * 8)];
      }
#pragma unroll
      for (int i = 0; i < 4; i++)
#pragma unroll
        for (int j = 0; j < 4; j++)
          acc[i][j] = __builtin_amdgcn_mfma_f32_16x16x32_bf16(a[i], b[j], acc[i][j], 0, 0, 0);
    }
  }
  // epilogue: C/D layout col=lane&15, row=quad*4+reg; fused per-col stats
  float* st = stats + (size_t)(m0 >> 15) * HH * 2;   // graph of this row-tile
#pragma unroll
  for (int j = 0; j < 4; j++) {
    int col = n0 + wc * 64 + j * 16 + fm;
    float bj = bias[col];
    float s = 0.f, q = 0.f;
#pragma unroll
    for (int i = 0; i < 4; i++) {
      int row = m0 + wr * 64 + i * 16 + quad * 4;
#pragma unroll
      for (int r = 0; r < 4; r++) {
        float v = acc[i][j][r] + bj;
        C[(size_t)(row + r) * HH + col] = (uint16_t)f2bf_u(v);
        s += v; q += v * v;
      }
    }
    s += __shfl_xor(s, 16); s += __shfl_xor(s, 32);
    q += __shfl_xor(q, 16); q += __shfl_xor(q, 32);
    if (quad == 0) {
      atomicAdd(&st[col * 2], s);
      atomicAdd(&st[col * 2 + 1], q);
    }
  }
}

// ---------- finalize BN: scale/shift per (graph, col) ----------
__global__ void finalize_kernel(const float* __restrict__ stats, const float* __restrict__ gamma,
                                const float* __restrict__ beta, float* __restrict__ scsh) {
  int i = blockIdx.x * 512 + threadIdx.x;   // < 1024
  int c = i & 511;
  float s = stats[i * 2], q = stats[i * 2 + 1];
  float mu = s * (1.f / (float)NN);
  float var = fmaxf(q * (1.f / (float)NN) - mu * mu, 0.f);
  float sc = gamma[c] * rsqrtf(var + BN_EPS);
  scsh[i * 2] = sc;
  scsh[i * 2 + 1] = beta[c] - mu * sc;
}

// ---------- BN+ReLU + per-graph-id readout sums (layer 2; h2 never materialized) ----------
__global__ void bn2_readout(const uint16_t* __restrict__ z, const float* __restrict__ scsh,
                            const int* __restrict__ gids1, const int* __restrict__ gids2,
                            float* __restrict__ readout, float* __restrict__ cnt) {
  int blk = blockIdx.x;                // 512 blocks x 128 rows (within one 512-row subgraph)
  int r0 = blk * 128;
  int g = r0 >> 15;
  int lr = r0 & (NN - 1);
  int gid = (g ? gids2 : gids1)[lr];
  int t = threadIdx.x;
  int c = t * 2;
  const float* ss = scsh + (size_t)g * HH * 2;
  float sc0 = ss[c * 2], sh0 = ss[c * 2 + 1];
  float sc1 = ss[(c + 1) * 2], sh1 = ss[(c + 1) * 2 + 1];
  const uint32_t* p = (const uint32_t*)z + (size_t)r0 * 256 + t;
  float a0 = 0, a1 = 0;
  for (int r = 0; r < 128; r++) {
    uint32_t w = p[(size_t)r * 256];
    a0 += fmaxf(fmaf(bflo(w), sc0, sh0), 0.f);
    a1 += fmaxf(fmaf(bfhi(w), sc1, sh1), 0.f);
  }
  float* ro = readout + ((size_t)g * BB + gid) * HH;
  atomicAdd(&ro[c], a0);
  atomicAdd(&ro[c + 1], a1);
  if (t == 0) atomicAdd(&cnt[g * BB + gid], 128.f);
}

// ---------- head: concat -> fc relu -> fc2 sigmoid ----------
__global__ void final_kernel(const float* __restrict__ readout, const float* __restrict__ cnt,
                             const float* __restrict__ Wfc, const float* __restrict__ bfc,
                             const float* __restrict__ Wfc2, const float* __restrict__ bfc2,
                             float* __restrict__ out) {
  __shared__ float x[1024];
  __shared__ float red[256];
  int b = blockIdx.x, t = threadIdx.x;
  for (int i = t; i < 1024; i += 256) {
    int g = i >> 9, c = i & 511;
    float cc = cnt[g * BB + b];
    x[i] = readout[((size_t)g * BB + b) * HH + c] / fmaxf(cc, 1.f);
  }
  __syncthreads();
  float acc = bfc[t];
  for (int i = 0; i < 1024; i++) acc = fmaf(x[i], Wfc[(size_t)i * 256 + t], acc);
  red[t] = fmaxf(acc, 0.f) * Wfc2[t];
  __syncthreads();
  for (int s = 128; s > 0; s >>= 1) {
    if (t < s) red[t] += red[t + s];
    __syncthreads();
  }
  if (t == 0) out[b] = 1.f / (1.f + expf(-(red[0] + bfc2[0])));
}

// ---------- launch ----------
extern "C" void kernel_launch(void* const* d_in, const int* in_sizes, int n_in,
                              void* d_out, int out_size, void* d_ws, size_t ws_size,
                              hipStream_t stream) {
  const float* x1 = (const float*)d_in[0];
  const float* x2 = (const float*)d_in[1];
  const int* src1 = (const int*)d_in[2];
  const int* dst1 = (const int*)d_in[3];
  const int* src2 = (const int*)d_in[4];
  const int* dst2 = (const int*)d_in[5];
  const int* gids1 = (const int*)d_in[6];
  const int* gids2 = (const int*)d_in[7];
  const float* Wi = (const float*)d_in[8];
  const float* bi = (const float*)d_in[9];
  const float* W1 = (const float*)d_in[10];
  const float* b1 = (const float*)d_in[11];
  const float* W2 = (const float*)d_in[12];
  const float* b2 = (const float*)d_in[13];
  const float* gamma1 = (const float*)d_in[14];
  const float* beta1 = (const float*)d_in[15];
  const float* gamma2 = (const float*)d_in[16];
  const float* beta2 = (const float*)d_in[17];
  const float* Wfc = (const float*)d_in[18];
  const float* bfc = (const float*)d_in[19];
  const float* Wfc2 = (const float*)d_in[20];
  const float* bfc2 = (const float*)d_in[21];
  float* out = (float*)d_out;

  // workspace layout (256B-aligned slabs)
  size_t off = 0;
  auto alloc = [&](size_t bytes) -> void* {
    void* p = (char*)d_ws + off;
    off += (bytes + 255) & ~(size_t)255;
    return p;
  };
  uint16_t* buf0 = (uint16_t*)alloc((size_t)MM * HH * 2);
  uint16_t* buf1 = (uint16_t*)alloc((size_t)MM * HH * 2);
  uint16_t* Wt1 = (uint16_t*)alloc((size_t)HH * HH * 2);
  uint16_t* Wt2 = (uint16_t*)alloc((size_t)HH * HH * 2);
  int* csr = (int*)alloc((size_t)2 * EE * 4);
  int* offsets = (int*)alloc((size_t)2 * (NN + 1) * 4);
  int* cursor = (int*)alloc((size_t)2 * NN * 4);
  float* xa = (float*)alloc((size_t)MM * DIN * 4);
  size_t zero_begin = off;
  int* deg_cnt = (int*)alloc((size_t)2 * NN * 4);
  float* stats1 = (float*)alloc((size_t)2 * HH * 2 * 4);
  float* stats2 = (float*)alloc((size_t)2 * HH * 2 * 4);
  float* readout = (float*)alloc((size_t)2 * BB * HH * 4);
  float* cnt = (float*)alloc((size_t)2 * BB * 4);
  size_t zero_end = off;
  float* scsh1 = (float*)alloc((size_t)2 * HH * 2 * 4);
  float* scsh2 = (float*)alloc((size_t)2 * HH * 2 * 4);
  (void)ws_size; (void)in_sizes; (void)n_in; (void)out_size;

  hipMemsetAsync((char*)d_ws + zero_begin, 0, zero_end - zero_begin, stream);

  // weights + CSR build
  prep_w<<<2048, 256, 0, stream>>>(W1, W2, Wt1, Wt2);
  deg_kernel<<<2048, 256, 0, stream>>>(dst1, dst2, deg_cnt);
  scan_kernel<<<2, 1024, 0, stream>>>(deg_cnt, offsets, cursor);
  scatter_kernel<<<2048, 256, 0, stream>>>(src1, dst1, src2, dst2, cursor, csr);

  // layer 1 (agg folded into x-space): xa -> u1 = xa@Wi + bi*(1+degflag) -> gemm+stats
  xagg_kernel<<<MM / 256, 256, 0, stream>>>(x1, x2, csr, offsets, xa);
  h0u_kernel<<<MM / 128, 256, 0, stream>>>(xa, Wi, bi, offsets, buf0);
  gemm_kernel<<<dim3(MM / 128, HH / 128), 256, 0, stream>>>(buf0, Wt1, b1, buf1, stats1);
  finalize_kernel<<<2, 512, 0, stream>>>(stats1, gamma1, beta1, scsh1);

  // layer 2: aggbn(z1)->u2 ; gemm+stats ; finalize ; bn2+readout
  aggbn_kernel<<<MM / 4, 256, 0, stream>>>(buf1, buf0, csr, offsets, scsh1);
  gemm_kernel<<<dim3(MM / 128, HH / 128), 256, 0, stream>>>(buf0, Wt2, b2, buf1, stats2);
  finalize_kernel<<<2, 512, 0, stream>>>(stats2, gamma2, beta2, scsh2);
  bn2_readout<<<MM / 128, 256, 0, stream>>>(buf1, scsh2, gids1, gids2, readout, cnt);

  // head
  final_kernel<<<BB, 256, 0, stream>>>(readout, cnt, Wfc, bfc, Wfc2, bfc2, out);
}

// Round 5
// 522.964 us; speedup vs baseline: 1.2076x; 1.2076x over previous
//
#include <hip/hip_runtime.h>
#include <hip/hip_bf16.h>
#include <cstdint>

// Problem constants (fixed by the reference harness)
#define NN 32768      // nodes per graph
#define EE 262144     // edges per graph
#define MM 65536      // 2*NN combined rows
#define HH 512
#define BB 64
#define DIN 20
#define BN_EPS 1e-5f

// ---------- bf16 helpers (bit-level, fast) ----------
__device__ __forceinline__ float bflo(uint32_t w) { return __builtin_bit_cast(float, w << 16); }
__device__ __forceinline__ float bfhi(uint32_t w) { return __builtin_bit_cast(float, w & 0xffff0000u); }
__device__ __forceinline__ uint32_t f2bf_u(float f) {
  uint32_t u = __builtin_bit_cast(uint32_t, f);
  return (u + 0x7fffu + ((u >> 16) & 1u)) >> 16;   // RTNE
}
__device__ __forceinline__ uint32_t pack2(float lo, float hi) {
  return f2bf_u(lo) | (f2bf_u(hi) << 16);
}

typedef __bf16 bf16x8 __attribute__((ext_vector_type(8)));
typedef float f32x4 __attribute__((ext_vector_type(4)));

__device__ __forceinline__ void gl2lds16(const void* g, void* l) {
  __builtin_amdgcn_global_load_lds(
      (const __attribute__((address_space(1))) void*)g,
      (__attribute__((address_space(3))) void*)l, 16, 0, 0);
}

// ---------- prep: W1/W2 fp32 [k][n] -> bf16 transposed [n][k] ----------
__global__ void prep_w(const float* __restrict__ W1, const float* __restrict__ W2,
                       uint16_t* __restrict__ Wt1, uint16_t* __restrict__ Wt2) {
  int idx = blockIdx.x * 256 + threadIdx.x;     // < 2*512*512
  int which = idx >> 18;
  int i = idx & 0x3ffff;
  int n = i >> 9, k = i & 511;
  const float* W = which ? W2 : W1;
  uint16_t* Wt = which ? Wt2 : Wt1;
  Wt[i] = (uint16_t)f2bf_u(W[(size_t)k * HH + n]);
}

// ---------- CSR build ----------
__global__ void deg_kernel(const int* __restrict__ dst1, const int* __restrict__ dst2,
                           int* __restrict__ deg_cnt) {
  int e = blockIdx.x * 256 + threadIdx.x;       // < 2*EE
  int g = e >> 18, le = e & 0x3ffff;
  int d = (g ? dst2 : dst1)[le];
  atomicAdd(&deg_cnt[g * NN + d], 1);
}

__global__ void scan_kernel(const int* __restrict__ deg_cnt, int* __restrict__ offsets,
                            int* __restrict__ cursor) {
  int g = blockIdx.x;
  const int* d = deg_cnt + g * NN;
  int* off = offsets + g * (NN + 1);
  int* cur = cursor + g * NN;
  int t = threadIdx.x;                          // 1024 threads
  int base = t * 32;
  int loc[32]; int s = 0;
#pragma unroll
  for (int i = 0; i < 32; i++) { loc[i] = d[base + i]; s += loc[i]; }
  __shared__ int sm[1024];
  sm[t] = s; __syncthreads();
  for (int ofs = 1; ofs < 1024; ofs <<= 1) {
    int v = sm[t];
    int add = (t >= ofs) ? sm[t - ofs] : 0;
    __syncthreads();
    sm[t] = v + add;
    __syncthreads();
  }
  int run = (t == 0) ? 0 : sm[t - 1];
#pragma unroll
  for (int i = 0; i < 32; i++) { off[base + i] = run; cur[base + i] = run; run += loc[i]; }
  if (t == 1023) off[NN] = run;
}

__global__ void scatter_kernel(const int* __restrict__ src1, const int* __restrict__ dst1,
                               const int* __restrict__ src2, const int* __restrict__ dst2,
                               int* __restrict__ cursor, int* __restrict__ csr) {
  int e = blockIdx.x * 256 + threadIdx.x;       // < 2*EE
  int g = e >> 18, le = e & 0x3ffff;
  int d = (g ? dst2 : dst1)[le];
  int s = (g ? src2 : src1)[le];
  int pos = atomicAdd(&cursor[g * NN + d], 1);
  csr[g * EE + pos] = s;
}

// ---------- xagg: xa = x + mean_{in-neighbors} x  (fp32, 20-dim; x fits in L2) ----------
__global__ void xagg_kernel(const float* __restrict__ x1, const float* __restrict__ x2,
                            const int* __restrict__ csr, const int* __restrict__ offsets,
                            float* __restrict__ xa) {
  int nid = blockIdx.x * 256 + threadIdx.x;     // [0, MM)
  int g = nid >> 15, n = nid & (NN - 1);
  const float* xg = g ? x2 : x1;
  const int* off = offsets + g * (NN + 1);
  int e0 = off[n], e1 = off[n + 1];
  const int* cs = csr + g * EE;
  float4 a4[5] = {};
  for (int e = e0; e < e1; e++) {
    const float4* xr = (const float4*)(xg + (size_t)cs[e] * DIN);
#pragma unroll
    for (int k = 0; k < 5; k++) {
      float4 v = xr[k];
      a4[k].x += v.x; a4[k].y += v.y; a4[k].z += v.z; a4[k].w += v.w;
    }
  }
  float inv = (e1 > e0) ? 1.f / (float)(e1 - e0) : 0.f;
  const float4* xs = (const float4*)(xg + (size_t)n * DIN);
  float4* xo = (float4*)(xa + (size_t)nid * DIN);
#pragma unroll
  for (int k = 0; k < 5; k++) {
    float4 v = xs[k];
    float4 o;
    o.x = v.x + a4[k].x * inv; o.y = v.y + a4[k].y * inv;
    o.z = v.z + a4[k].z * inv; o.w = v.w + a4[k].w * inv;
    xo[k] = o;
  }
}

// ---------- h0u: u1 = xa @ Wi + bi*(1+[deg>0])  (fp32 in, bf16 out) ----------
__global__ __launch_bounds__(256) void h0u_kernel(const float* __restrict__ xa,
                          const float* __restrict__ Wi, const float* __restrict__ bi,
                          const int* __restrict__ offsets, uint16_t* __restrict__ u) {
  int t = threadIdx.x;
  int col0 = (t & 127) * 4;         // 128 threads cover 512 cols
  int rhalf = t >> 7;               // two row-interleaved halves
  int r0 = blockIdx.x * 128;        // 512 blocks x 128 rows; never straddles graphs
  int g = r0 >> 15;
  const int* off = offsets + g * (NN + 1);

  float w[DIN][4];
#pragma unroll
  for (int k = 0; k < DIN; k++) {
    float4 wv = *(const float4*)(Wi + (size_t)k * HH + col0);
    w[k][0] = wv.x; w[k][1] = wv.y; w[k][2] = wv.z; w[k][3] = wv.w;
  }
  float4 bv = *(const float4*)(bi + col0);

  for (int rr = 0; rr < 64; rr++) {
    int row = rr * 2 + rhalf;       // uniform within a wave
    int grow = r0 + row;
    int n = grow & (NN - 1);
    float bf = (off[n + 1] - off[n] > 0) ? 2.f : 1.f;   // wave-uniform
    const float* xr = xa + (size_t)grow * DIN;
    float a0 = bv.x * bf, a1 = bv.y * bf, a2 = bv.z * bf, a3 = bv.w * bf;
#pragma unroll
    for (int k = 0; k < DIN; k++) {
      float xv = xr[k];             // wave-uniform -> s_load broadcast
      a0 = fmaf(xv, w[k][0], a0);
      a1 = fmaf(xv, w[k][1], a1);
      a2 = fmaf(xv, w[k][2], a2);
      a3 = fmaf(xv, w[k][3], a3);
    }
    uint2 o;
    o.x = pack2(a0, a1); o.y = pack2(a2, a3);
    *(uint2*)(u + (size_t)grow * HH + col0) = o;
  }
}

// ---------- aggbn: u2 = bnrelu(z1) + mean_{nbr} bnrelu(z1_j)  (one wave per node) ----------
__global__ void aggbn_kernel(const uint16_t* __restrict__ z, uint16_t* __restrict__ u,
                             const int* __restrict__ csr, const int* __restrict__ offsets,
                             const float* __restrict__ scsh) {
  int wid = (blockIdx.x * 256 + threadIdx.x) >> 6;   // node id in [0, MM)
  int lane = threadIdx.x & 63;
  int g = wid >> 15, n = wid & (NN - 1);
  const int* off = offsets + g * (NN + 1);
  int e0 = off[n], e1 = off[n + 1];
  const int* cs = csr + g * EE;
  const uint32_t* hb = (const uint32_t*)z;           // 256 u32 per row
  const float4* ssp = (const float4*)(scsh + (size_t)g * HH * 2 + lane * 16);
  float4 ss0 = ssp[0], ss1 = ssp[1], ss2 = ssp[2], ss3 = ssp[3];
  float sc[8] = {ss0.x, ss0.z, ss1.x, ss1.z, ss2.x, ss2.z, ss3.x, ss3.z};
  float sh[8] = {ss0.y, ss0.w, ss1.y, ss1.w, ss2.y, ss2.w, ss3.y, ss3.w};
  float acc[8] = {0.f, 0.f, 0.f, 0.f, 0.f, 0.f, 0.f, 0.f};
  for (int e = e0; e < e1; e++) {
    int s = cs[e];
    uint4 v = *(const uint4*)(hb + ((size_t)(g * NN + s)) * 256 + lane * 4);
    uint32_t wv[4] = {v.x, v.y, v.z, v.w};
#pragma unroll
    for (int i = 0; i < 4; i++) {
      acc[2 * i]     += fmaxf(fmaf(bflo(wv[i]), sc[2 * i],     sh[2 * i]),     0.f);
      acc[2 * i + 1] += fmaxf(fmaf(bfhi(wv[i]), sc[2 * i + 1], sh[2 * i + 1]), 0.f);
    }
  }
  float inv = (e1 > e0) ? 1.f / (float)(e1 - e0) : 0.f;
  uint4 hv = *(const uint4*)(hb + (size_t)wid * 256 + lane * 4);
  uint32_t wv[4] = {hv.x, hv.y, hv.z, hv.w};
  float o[8];
#pragma unroll
  for (int i = 0; i < 4; i++) {
    o[2 * i]     = fmaxf(fmaf(bflo(wv[i]), sc[2 * i],     sh[2 * i]),     0.f) + acc[2 * i] * inv;
    o[2 * i + 1] = fmaxf(fmaf(bfhi(wv[i]), sc[2 * i + 1], sh[2 * i + 1]), 0.f) + acc[2 * i + 1] * inv;
  }
  uint4 ov;
  ov.x = pack2(o[0], o[1]); ov.y = pack2(o[2], o[3]); ov.z = pack2(o[4], o[5]); ov.w = pack2(o[6], o[7]);
  *(uint4*)((uint32_t*)u + (size_t)wid * 256 + lane * 4) = ov;
}

// ---------- GEMM: C[M,512] = A[M,512](bf16) @ Wt^T + bias ----------
// 128x128 tile, BK=64, 4 waves (2x2), XOR-swizzled LDS (0 bank conflicts, R4-verified).
// Stats de-fused: the R2->R3 fused-atomic epilogue cost >= 55 us of fabric
// serialization (1M device-scope atomics onto a 16 KB region) -- clean epilogue here.
__global__ __launch_bounds__(256) void gemm_kernel(const uint16_t* __restrict__ A,
                                                   const uint16_t* __restrict__ Bt,
                                                   const float* __restrict__ bias,
                                                   uint16_t* __restrict__ C) {
  __shared__ uint16_t sA[128 * 64];
  __shared__ uint16_t sB[128 * 64];
  const int tid = threadIdx.x;
  const int wave = tid >> 6;
  const int lane = tid & 63;
  const int m0 = blockIdx.x * 128;
  const int n0 = blockIdx.y * 128;
  const int fm = lane & 15;
  const int fm7 = fm & 7;
  const int quad = lane >> 4;
  const int wr = wave >> 1, wc = wave & 1;

  // staging: lane covers (r_loc = lane>>3, k8 slot = lane&7); global k8 is XORed
  const int r_loc = lane >> 3;
  const int k8slot = lane & 7;
  const int k8g = k8slot ^ r_loc;
  const int rbase = wave * 32;                  // wave stages rows [wave*32, wave*32+32)

  f32x4 acc[4][4] = {};
  for (int k0 = 0; k0 < HH; k0 += 64) {
    __syncthreads();
#pragma unroll
    for (int t = 0; t < 4; t++) {
      int R = rbase + t * 8 + r_loc;
      gl2lds16(A  + (size_t)(m0 + R) * HH + k0 + k8g * 8, &sA[R * 64 + k8slot * 8]);
      gl2lds16(Bt + (size_t)(n0 + R) * HH + k0 + k8g * 8, &sB[R * 64 + k8slot * 8]);
    }
    __syncthreads();
#pragma unroll
    for (int s2 = 0; s2 < 2; s2++) {
      const int k8 = s2 * 4 + quad;
      bf16x8 a[4], b[4];
#pragma unroll
      for (int i = 0; i < 4; i++) {
        int r = wr * 64 + i * 16 + fm;
        a[i] = *(const bf16x8*)&sA[r * 64 + ((k8 ^ fm7) * 8)];
      }
#pragma unroll
      for (int j = 0; j < 4; j++) {
        int r = wc * 64 + j * 16 + fm;
        b[j] = *(const bf16x8*)&sB[r * 64 + ((k8 ^ fm7) * 8)];
      }
#pragma unroll
      for (int i = 0; i < 4; i++)
#pragma unroll
        for (int j = 0; j < 4; j++)
          acc[i][j] = __builtin_amdgcn_mfma_f32_16x16x32_bf16(a[i], b[j], acc[i][j], 0, 0, 0);
    }
  }
  // epilogue: C/D layout col=lane&15, row=quad*4+reg
#pragma unroll
  for (int j = 0; j < 4; j++) {
    int col = n0 + wc * 64 + j * 16 + fm;
    float bj = bias[col];
#pragma unroll
    for (int i = 0; i < 4; i++) {
      int row = m0 + wr * 64 + i * 16 + quad * 4;
#pragma unroll
      for (int r = 0; r < 4; r++)
        C[(size_t)(row + r) * HH + col] = (uint16_t)f2bf_u(acc[i][j][r] + bj);
    }
  }
}

// ---------- per-column stats (sum, sumsq) per graph ----------
// 256-row blocks: 4x fewer atomics than the R1 version (262K total), coalesced reads.
__global__ void stats_kernel(const uint16_t* __restrict__ z, float* __restrict__ stats) {
  int blk = blockIdx.x;                 // 256 blocks x 256 rows; never straddles graphs
  int r0 = blk * 256;
  int g = r0 >> 15;
  int t = threadIdx.x;                  // 256 threads, col pair c = t*2
  int c = t * 2;
  const uint32_t* p = (const uint32_t*)z + (size_t)r0 * 256 + t;
  float s0 = 0, s1 = 0, q0 = 0, q1 = 0;
  for (int r = 0; r < 256; r++) {
    uint32_t w = p[(size_t)r * 256];
    float f0 = bflo(w), f1 = bfhi(w);
    s0 += f0; q0 += f0 * f0; s1 += f1; q1 += f1 * f1;
  }
  float* st = stats + (size_t)g * HH * 2;
  atomicAdd(&st[c * 2 + 0], s0);
  atomicAdd(&st[c * 2 + 1], q0);
  atomicAdd(&st[(c + 1) * 2 + 0], s1);
  atomicAdd(&st[(c + 1) * 2 + 1], q1);
}

// ---------- finalize BN: scale/shift per (graph, col) ----------
__global__ void finalize_kernel(const float* __restrict__ stats, const float* __restrict__ gamma,
                                const float* __restrict__ beta, float* __restrict__ scsh) {
  int i = blockIdx.x * 512 + threadIdx.x;   // < 1024
  int c = i & 511;
  float s = stats[i * 2], q = stats[i * 2 + 1];
  float mu = s * (1.f / (float)NN);
  float var = fmaxf(q * (1.f / (float)NN) - mu * mu, 0.f);
  float sc = gamma[c] * rsqrtf(var + BN_EPS);
  scsh[i * 2] = sc;
  scsh[i * 2 + 1] = beta[c] - mu * sc;
}

// ---------- BN+ReLU + per-graph-id readout sums (layer 2; h2 never materialized) ----------
__global__ void bn2_readout(const uint16_t* __restrict__ z, const float* __restrict__ scsh,
                            const int* __restrict__ gids1, const int* __restrict__ gids2,
                            float* __restrict__ readout, float* __restrict__ cnt) {
  int blk = blockIdx.x;                // 512 blocks x 128 rows (within one 512-row subgraph)
  int r0 = blk * 128;
  int g = r0 >> 15;
  int lr = r0 & (NN - 1);
  int gid = (g ? gids2 : gids1)[lr];
  int t = threadIdx.x;
  int c = t * 2;
  const float* ss = scsh + (size_t)g * HH * 2;
  float sc0 = ss[c * 2], sh0 = ss[c * 2 + 1];
  float sc1 = ss[(c + 1) * 2], sh1 = ss[(c + 1) * 2 + 1];
  const uint32_t* p = (const uint32_t*)z + (size_t)r0 * 256 + t;
  float a0 = 0, a1 = 0;
  for (int r = 0; r < 128; r++) {
    uint32_t w = p[(size_t)r * 256];
    a0 += fmaxf(fmaf(bflo(w), sc0, sh0), 0.f);
    a1 += fmaxf(fmaf(bfhi(w), sc1, sh1), 0.f);
  }
  float* ro = readout + ((size_t)g * BB + gid) * HH;
  atomicAdd(&ro[c], a0);
  atomicAdd(&ro[c + 1], a1);
  if (t == 0) atomicAdd(&cnt[g * BB + gid], 128.f);
}

// ---------- head: concat -> fc relu -> fc2 sigmoid ----------
__global__ void final_kernel(const float* __restrict__ readout, const float* __restrict__ cnt,
                             const float* __restrict__ Wfc, const float* __restrict__ bfc,
                             const float* __restrict__ Wfc2, const float* __restrict__ bfc2,
                             float* __restrict__ out) {
  __shared__ float x[1024];
  __shared__ float red[256];
  int b = blockIdx.x, t = threadIdx.x;
  for (int i = t; i < 1024; i += 256) {
    int g = i >> 9, c = i & 511;
    float cc = cnt[g * BB + b];
    x[i] = readout[((size_t)g * BB + b) * HH + c] / fmaxf(cc, 1.f);
  }
  __syncthreads();
  float acc = bfc[t];
  for (int i = 0; i < 1024; i++) acc = fmaf(x[i], Wfc[(size_t)i * 256 + t], acc);
  red[t] = fmaxf(acc, 0.f) * Wfc2[t];
  __syncthreads();
  for (int s = 128; s > 0; s >>= 1) {
    if (t < s) red[t] += red[t + s];
    __syncthreads();
  }
  if (t == 0) out[b] = 1.f / (1.f + expf(-(red[0] + bfc2[0])));
}

// ---------- launch ----------
extern "C" void kernel_launch(void* const* d_in, const int* in_sizes, int n_in,
                              void* d_out, int out_size, void* d_ws, size_t ws_size,
                              hipStream_t stream) {
  const float* x1 = (const float*)d_in[0];
  const float* x2 = (const float*)d_in[1];
  const int* src1 = (const int*)d_in[2];
  const int* dst1 = (const int*)d_in[3];
  const int* src2 = (const int*)d_in[4];
  const int* dst2 = (const int*)d_in[5];
  const int* gids1 = (const int*)d_in[6];
  const int* gids2 = (const int*)d_in[7];
  const float* Wi = (const float*)d_in[8];
  const float* bi = (const float*)d_in[9];
  const float* W1 = (const float*)d_in[10];
  const float* b1 = (const float*)d_in[11];
  const float* W2 = (const float*)d_in[12];
  const float* b2 = (const float*)d_in[13];
  const float* gamma1 = (const float*)d_in[14];
  const float* beta1 = (const float*)d_in[15];
  const float* gamma2 = (const float*)d_in[16];
  const float* beta2 = (const float*)d_in[17];
  const float* Wfc = (const float*)d_in[18];
  const float* bfc = (const float*)d_in[19];
  const float* Wfc2 = (const float*)d_in[20];
  const float* bfc2 = (const float*)d_in[21];
  float* out = (float*)d_out;

  // workspace layout (256B-aligned slabs)
  size_t off = 0;
  auto alloc = [&](size_t bytes) -> void* {
    void* p = (char*)d_ws + off;
    off += (bytes + 255) & ~(size_t)255;
    return p;
  };
  uint16_t* buf0 = (uint16_t*)alloc((size_t)MM * HH * 2);
  uint16_t* buf1 = (uint16_t*)alloc((size_t)MM * HH * 2);
  uint16_t* Wt1 = (uint16_t*)alloc((size_t)HH * HH * 2);
  uint16_t* Wt2 = (uint16_t*)alloc((size_t)HH * HH * 2);
  int* csr = (int*)alloc((size_t)2 * EE * 4);
  int* offsets = (int*)alloc((size_t)2 * (NN + 1) * 4);
  int* cursor = (int*)alloc((size_t)2 * NN * 4);
  float* xa = (float*)alloc((size_t)MM * DIN * 4);
  size_t zero_begin = off;
  int* deg_cnt = (int*)alloc((size_t)2 * NN * 4);
  float* stats1 = (float*)alloc((size_t)2 * HH * 2 * 4);
  float* stats2 = (float*)alloc((size_t)2 * HH * 2 * 4);
  float* readout = (float*)alloc((size_t)2 * BB * HH * 4);
  float* cnt = (float*)alloc((size_t)2 * BB * 4);
  size_t zero_end = off;
  float* scsh1 = (float*)alloc((size_t)2 * HH * 2 * 4);
  float* scsh2 = (float*)alloc((size_t)2 * HH * 2 * 4);
  (void)ws_size; (void)in_sizes; (void)n_in; (void)out_size;

  hipMemsetAsync((char*)d_ws + zero_begin, 0, zero_end - zero_begin, stream);

  // weights + CSR build
  prep_w<<<2048, 256, 0, stream>>>(W1, W2, Wt1, Wt2);
  deg_kernel<<<2048, 256, 0, stream>>>(dst1, dst2, deg_cnt);
  scan_kernel<<<2, 1024, 0, stream>>>(deg_cnt, offsets, cursor);
  scatter_kernel<<<2048, 256, 0, stream>>>(src1, dst1, src2, dst2, cursor, csr);

  // layer 1 (agg folded into x-space): xa -> u1 = xa@Wi + bi*(1+degflag) -> gemm -> stats
  xagg_kernel<<<MM / 256, 256, 0, stream>>>(x1, x2, csr, offsets, xa);
  h0u_kernel<<<MM / 128, 256, 0, stream>>>(xa, Wi, bi, offsets, buf0);
  gemm_kernel<<<dim3(MM / 128, HH / 128), 256, 0, stream>>>(buf0, Wt1, b1, buf1);
  stats_kernel<<<MM / 256, 256, 0, stream>>>(buf1, stats1);
  finalize_kernel<<<2, 512, 0, stream>>>(stats1, gamma1, beta1, scsh1);

  // layer 2: aggbn(z1)->u2 ; gemm ; stats ; finalize ; bn2+readout
  aggbn_kernel<<<MM / 4, 256, 0, stream>>>(buf1, buf0, csr, offsets, scsh1);
  gemm_kernel<<<dim3(MM / 128, HH / 128), 256, 0, stream>>>(buf0, Wt2, b2, buf1);
  stats_kernel<<<MM / 256, 256, 0, stream>>>(buf1, stats2);
  finalize_kernel<<<2, 512, 0, stream>>>(stats2, gamma2, beta2, scsh2);
  bn2_readout<<<MM / 128, 256, 0, stream>>>(buf1, scsh2, gids1, gids2, readout, cnt);

  // head
  final_kernel<<<BB, 256, 0, stream>>>(readout, cnt, Wfc, bfc, Wfc2, bfc2, out);
}